// Round 14
// baseline (354.083 us; speedup 1.0000x reference)
//
#include <hip/hip_runtime.h>
#include <math.h>

#define EPS  1e-6f
#define DD   256
#define NSUP 5
#define NQ   8
#define SEQ  13
#define L2E  1.44269504088896f
#define LN2  0.693147180559945f
#define NEP  2048            // episodes
#define NROW 16384           // NEP*NQ query rows
#define NCOL 2048            // anchor columns

typedef short bf16x8 __attribute__((ext_vector_type(8)));
typedef unsigned short u16x4 __attribute__((ext_vector_type(4)));
typedef float f32x4  __attribute__((ext_vector_type(4)));

__device__ __forceinline__ ushort f2bf(float f) {
  union { float f; unsigned u; } v; v.f = f;
  unsigned r = v.u + 0x7FFFu + ((v.u >> 16) & 1u);   // round-to-nearest-even
  return (ushort)(r >> 16);
}
__device__ __forceinline__ float bf2f(short u) {
  union { unsigned u; float f; } v; v.u = ((unsigned)(unsigned short)u) << 16;
  return v.f;
}

// ---------------------------------------------------------------------------
// prep (r8-proven, unchanged)
// ---------------------------------------------------------------------------
__global__ __launch_bounds__(256) void proto_prep(
    const float* __restrict__ x, float* __restrict__ cb,
    ushort* __restrict__ Asw, ushort* __restrict__ Qsw,
    float* __restrict__ accum, int* __restrict__ fincount) {
  const int tid = threadIdx.x, g = tid >> 6, l = tid & 63;
  const int n = blockIdx.x * 4 + g;
  if (blockIdx.x == 0 && tid == 0) { accum[0] = 0.f; accum[1] = 0.f; fincount[0] = 0; }

  const float4* xr4 = (const float4*)(x + (size_t)n * SEQ * DD);

  const int d0   = l * 4;
  const int kk   = d0 >> 5, quad = (d0 >> 3) & 3, j = d0 & 7;   // j in {0,4}
  const size_t chunk_d = (size_t)kk * 64 + (size_t)quad * 16;

  float4 a = {0.f, 0.f, 0.f, 0.f};
  #pragma unroll
  for (int s = 0; s < NSUP; ++s) {
    float4 v = xr4[s * 64 + l];
    a.x += v.x; a.y += v.y; a.z += v.z; a.w += v.w;
  }
  a.x *= 0.2f; a.y *= 0.2f; a.z *= 0.2f; a.w *= 0.2f;
  {
    const size_t idx = (((size_t)(n >> 4) * 8) * 64 + chunk_d + (n & 15)) * 8 + j;
    u16x4 o = {f2bf(a.x), f2bf(a.y), f2bf(a.z), f2bf(a.w)};
    *(u16x4*)(Asw + idx) = o;
  }
  float s1 = a.x + a.y + a.z + a.w;
  float s2 = a.x * a.x + a.y * a.y + a.z * a.z + a.w * a.w;
  #pragma unroll
  for (int off = 32; off; off >>= 1) {
    s1 += __shfl_xor(s1, off);
    s2 += __shfl_xor(s2, off);
  }
  if (l == 0) cb[n] = -L2E * (s2 - 2.f * EPS * s1);

  #pragma unroll
  for (int s = 0; s < NQ; ++s) {
    float4 q = xr4[(NSUP + s) * 64 + l];
    const int row = n * NQ + s;
    const size_t idx = (((size_t)(row >> 4) * 8) * 64 + chunk_d + (row & 15)) * 8 + j;
    u16x4 o = {f2bf(q.x), f2bf(q.y), f2bf(q.z), f2bf(q.w)};
    *(u16x4*)(Qsw + idx) = o;
  }
}

// ---------------------------------------------------------------------------
// main (r25, unchanged — current best family, bit-exact): 512 blocks x 256
// thr, 2 blocks/CU, 256x256 tile, sets=4, XCD swizzle, direct partials.
// ---------------------------------------------------------------------------
__global__ __launch_bounds__(256, 2) void proto_main(
    const ushort* __restrict__ Qsw, const ushort* __restrict__ Asw,
    const float* __restrict__ cb, const int* __restrict__ label,
    float* __restrict__ partm, float* __restrict__ parts,
    int* __restrict__ partbi, float* __restrict__ slabws) {
  const int tid  = threadIdx.x;
  const int rowg = tid >> 6, lane = tid & 63;
  const int quad = lane >> 4, lcol = lane & 15;
  const int rb   = blockIdx.x & 63;
  const int colc = blockIdx.x >> 6;
  const int r0   = rb * 256;

  const bf16x8* qb = (const bf16x8*)Qsw;
  const bf16x8* bb = (const bf16x8*)Asw;

  __shared__ bf16x8 Bl[2][8][64];
  __shared__ float  sCb[256];

  sCb[tid] = cb[colc * 256 + tid];

  bf16x8 af[4][8];
  #pragma unroll
  for (int set = 0; set < 4; ++set) {
    const size_t base = ((size_t)(rb * 16 + rowg * 4 + set) * 8) * 64 + lane;
    #pragma unroll
    for (int kk = 0; kk < 8; ++kk) af[set][kk] = qb[base + (size_t)kk * 64];
  }

  float m[4][4], s[4][4];
  int   bi[4][4];
  #pragma unroll
  for (int set = 0; set < 4; ++set)
    #pragma unroll
    for (int i = 0; i < 4; ++i) {
      m[set][i] = -1e30f; s[set][i] = 0.f; bi[set][i] = 0x7fffffff;
    }

  const int kk0 = rowg * 2;
  auto stage = [&](int tl, int b) {
    const int T = colc * 16 + tl;
    #pragma unroll
    for (int k2 = 0; k2 < 2; ++k2) {
      const int kk = kk0 + k2;
      const ushort* src = Asw + (((size_t)T * 8 + kk) * 64 + lane) * 8;
      __builtin_amdgcn_global_load_lds(
          (const __attribute__((address_space(1))) void*)src,
          (__attribute__((address_space(3))) void*)&Bl[b][kk][0],
          16, 0, 0);
    }
  };

  auto compute = [&](int tl, int b) {
    f32x4 c0 = {0.f, 0.f, 0.f, 0.f}, c1 = {0.f, 0.f, 0.f, 0.f};
    f32x4 c2 = {0.f, 0.f, 0.f, 0.f}, c3 = {0.f, 0.f, 0.f, 0.f};
    #pragma unroll
    for (int kk = 0; kk < 8; ++kk) {
      bf16x8 bf = Bl[b][kk][lane];
      c0 = __builtin_amdgcn_mfma_f32_16x16x32_bf16(af[0][kk], bf, c0, 0, 0, 0);
      c1 = __builtin_amdgcn_mfma_f32_16x16x32_bf16(af[1][kk], bf, c1, 0, 0, 0);
      c2 = __builtin_amdgcn_mfma_f32_16x16x32_bf16(af[2][kk], bf, c2, 0, 0, 0);
      c3 = __builtin_amdgcn_mfma_f32_16x16x32_bf16(af[3][kk], bf, c3, 0, 0, 0);
    }
    const int   lcIdx  = tl * 16 + lcol;
    const int   colIdx = colc * 256 + lcIdx;
    const float cbv    = sCb[lcIdx];
    #pragma unroll
    for (int set = 0; set < 4; ++set) {
      #pragma unroll
      for (int i = 0; i < 4; ++i) {
        float cv = (set == 0) ? c0[i] : (set == 1) ? c1[i]
                 : (set == 2) ? c2[i] : c3[i];
        float v2 = fmaf(cv, 2.f * L2E, cbv);
        float dv = v2 - m[set][i];
        bool  gt = dv > 0.f;
        float e  = exp2f(-fabsf(dv));
        s[set][i]  = fmaf(s[set][i], gt ? e : 1.f, gt ? 1.f : e);
        m[set][i]  = fmaxf(m[set][i], v2);
        bi[set][i] = gt ? colIdx : bi[set][i];
      }
    }
  };

  stage(0, 0);
  __syncthreads();

  #pragma unroll 1
  for (int t = 0; t < 16; t += 2) {
    stage(t + 1, 1);
    compute(t, 0);
    __syncthreads();
    if (t + 2 < 16) stage(t + 2, 0);
    compute(t + 1, 1);
    __syncthreads();
  }

  #pragma unroll
  for (int mask = 1; mask < 16; mask <<= 1) {
    #pragma unroll
    for (int set = 0; set < 4; ++set)
      #pragma unroll
      for (int i = 0; i < 4; ++i) {
        float om = __shfl_xor(m[set][i], mask);
        float os = __shfl_xor(s[set][i], mask);
        int   oi = __shfl_xor(bi[set][i], mask);
        float nm = fmaxf(m[set][i], om);
        s[set][i] = s[set][i] * exp2f(m[set][i] - nm) + os * exp2f(om - nm);
        bool better = (om > m[set][i]) || (om == m[set][i] && oi < bi[set][i]);
        bi[set][i] = better ? oi : bi[set][i];
        m[set][i]  = nm;
      }
  }

  if (lcol == 0) {
    #pragma unroll
    for (int set = 0; set < 4; ++set)
      #pragma unroll
      for (int i = 0; i < 4; ++i) {
        const int row = r0 + rowg * 64 + set * 16 + quad * 4 + i;
        partm [colc * NROW + row] = m[set][i];
        parts [colc * NROW + row] = s[set][i];
        partbi[colc * NROW + row] = bi[set][i];
      }
  }

  if (colc == 0) {
    const int row = r0 + tid;
    const int lab = label[row >> 3];
    float dot = 0.f;
    #pragma unroll
    for (int kk = 0; kk < 8; ++kk) {
      const size_t qc = ((size_t)(row >> 4) * 8 + kk) * 64 + (row & 15);
      const size_t ac = ((size_t)(lab >> 4) * 8 + kk) * 64 + (lab & 15);
      #pragma unroll
      for (int qd = 0; qd < 4; ++qd) {
        bf16x8 qv = qb[qc + qd * 16];
        bf16x8 av = bb[ac + qd * 16];
        #pragma unroll
        for (int j = 0; j < 8; ++j) dot = fmaf(bf2f(qv[j]), bf2f(av[j]), dot);
      }
    }
    slabws[row] = fmaf(dot, 2.f * L2E, cb[lab]);
  }
}

// ---------------------------------------------------------------------------
// ABLATION PROBES (r26, diagnostic): re-run the main loop with components
// removed, x4 reps (so every probe exceeds the ~45 us fills and lands in the
// rocprof top-5). Outputs -> scratch; real results untouched.
// V=0 full | V=1 no-softmax (MFMA kept live, rule #17) | V=2 no-MFMA
// (softmax fed from staged B regs) | V=3 stage+barrier only.
// Components: SM = (p0-p1)/4 ; MFMA+ds = (p1-p3)/4 ; stage+bar = p3/4.
// ---------------------------------------------------------------------------
template<int V, int REPS>
__global__ __launch_bounds__(256, 2) void proto_probe(
    const ushort* __restrict__ Qsw, const ushort* __restrict__ Asw,
    const float* __restrict__ cb, float* __restrict__ scratch) {
  const int tid  = threadIdx.x;
  const int rowg = tid >> 6, lane = tid & 63;
  const int lcol = lane & 15;
  const int rb   = blockIdx.x & 63;
  const int colc = blockIdx.x >> 6;

  const bf16x8* qb = (const bf16x8*)Qsw;

  __shared__ bf16x8 Bl[2][8][64];
  __shared__ float  sCb[256];
  sCb[tid] = cb[colc * 256 + tid];

  bf16x8 af[4][8];
  #pragma unroll
  for (int set = 0; set < 4; ++set) {
    const size_t base = ((size_t)(rb * 16 + rowg * 4 + set) * 8) * 64 + lane;
    #pragma unroll
    for (int kk = 0; kk < 8; ++kk) af[set][kk] = qb[base + (size_t)kk * 64];
  }

  float m[4][4], s[4][4];
  int   bi[4][4];
  #pragma unroll
  for (int set = 0; set < 4; ++set)
    #pragma unroll
    for (int i = 0; i < 4; ++i) {
      m[set][i] = -1e30f; s[set][i] = 0.f; bi[set][i] = 0x7fffffff;
    }

  float keep = 0.f;
  const int kk0 = rowg * 2;
  auto stage = [&](int tl, int b) {
    const int T = colc * 16 + tl;
    #pragma unroll
    for (int k2 = 0; k2 < 2; ++k2) {
      const int kk = kk0 + k2;
      const ushort* src = Asw + (((size_t)T * 8 + kk) * 64 + lane) * 8;
      __builtin_amdgcn_global_load_lds(
          (const __attribute__((address_space(1))) void*)src,
          (__attribute__((address_space(3))) void*)&Bl[b][kk][0],
          16, 0, 0);
    }
  };

  stage(0, 0);
  __syncthreads();

  #pragma unroll 1
  for (int rep = 0; rep < REPS; ++rep) {
    #pragma unroll 1
    for (int t = 0; t < 16; ++t) {
      const int b = t & 1;
      stage((t + 1) & 15, b ^ 1);                    // ring across reps
      if constexpr (V != 3) {
        f32x4 c0 = {0.f,0.f,0.f,0.f}, c1 = {0.f,0.f,0.f,0.f};
        f32x4 c2 = {0.f,0.f,0.f,0.f}, c3 = {0.f,0.f,0.f,0.f};
        bf16x8 bfr[8];
        #pragma unroll
        for (int kk = 0; kk < 8; ++kk) bfr[kk] = Bl[b][kk][lane];
        if constexpr (V != 2) {
          #pragma unroll
          for (int kk = 0; kk < 8; ++kk) {
            c0 = __builtin_amdgcn_mfma_f32_16x16x32_bf16(af[0][kk], bfr[kk], c0, 0, 0, 0);
            c1 = __builtin_amdgcn_mfma_f32_16x16x32_bf16(af[1][kk], bfr[kk], c1, 0, 0, 0);
            c2 = __builtin_amdgcn_mfma_f32_16x16x32_bf16(af[2][kk], bfr[kk], c2, 0, 0, 0);
            c3 = __builtin_amdgcn_mfma_f32_16x16x32_bf16(af[3][kk], bfr[kk], c3, 0, 0, 0);
          }
        }
        if constexpr (V == 1) {
          keep += c0[0] + c1[0] + c2[0] + c3[0];     // MFMA live, no softmax
        } else {
          const int   lcIdx  = t * 16 + lcol;
          const int   colIdx = colc * 256 + lcIdx;
          const float cbv    = sCb[lcIdx];
          #pragma unroll
          for (int set = 0; set < 4; ++set) {
            #pragma unroll
            for (int i = 0; i < 4; ++i) {
              float cv;
              if constexpr (V == 0)
                cv = (set == 0) ? c0[i] : (set == 1) ? c1[i]
                   : (set == 2) ? c2[i] : c3[i];
              else
                cv = bf2f(bfr[set * 2 + (i >> 1)][(i & 1) * 4]);  // B-fed
              float v2 = fmaf(cv, 2.f * L2E, cbv);
              float dv = v2 - m[set][i];
              bool  gt = dv > 0.f;
              float e  = exp2f(-fabsf(dv));
              s[set][i]  = fmaf(s[set][i], gt ? e : 1.f, gt ? 1.f : e);
              m[set][i]  = fmaxf(m[set][i], v2);
              bi[set][i] = gt ? colIdx : bi[set][i];
            }
          }
        }
      }
      __syncthreads();
    }
  }

  #pragma unroll
  for (int set = 0; set < 4; ++set)
    #pragma unroll
    for (int i = 0; i < 4; ++i)
      keep += m[set][i] + s[set][i] + (float)bi[set][i];
  scratch[(size_t)blockIdx.x * 256 + tid] = keep;    // liveness anchor
}

// ---------------------------------------------------------------------------
// merge (r25, unchanged): 8-way chunk merge + finalize.
// ---------------------------------------------------------------------------
__global__ __launch_bounds__(256) void proto_merge(
    const float* __restrict__ partm, const float* __restrict__ parts,
    const int* __restrict__ partbi, const float* __restrict__ slabws,
    const int* __restrict__ label,
    float* __restrict__ accum, int* __restrict__ fincount,
    float* __restrict__ out) {
  const int tid = threadIdx.x, row = blockIdx.x * 256 + tid;
  const int wid = tid >> 6;

  float mm = partm[row], sv = parts[row];
  int   b  = partbi[row];
  #pragma unroll
  for (int c = 1; c < 8; ++c) {
    float om = partm[c * NROW + row], os = parts[c * NROW + row];
    int   oi = partbi[c * NROW + row];
    float nm = fmaxf(mm, om);
    sv = sv * exp2f(mm - nm) + os * exp2f(om - nm);
    bool better = (om > mm) || (om == mm && oi < b);
    b = better ? oi : b;
    mm = nm;
  }

  const int lb = label[row >> 3];
  float loss = LN2 * (mm + log2f(sv) - slabws[row]);
  float corr = (b == lb) ? 1.f : 0.f;

  #pragma unroll
  for (int mask = 32; mask; mask >>= 1) {
    loss += __shfl_xor(loss, mask);
    corr += __shfl_xor(corr, mask);
  }
  __shared__ float red[2][4];
  if ((tid & 63) == 0) { red[0][wid] = loss; red[1][wid] = corr; }
  __syncthreads();
  if (tid == 0) {
    float L = red[0][0] + red[0][1] + red[0][2] + red[0][3];
    float C = red[1][0] + red[1][1] + red[1][2] + red[1][3];
    atomicAdd(&accum[0], L);
    atomicAdd(&accum[1], C);
    __threadfence();
    if (atomicAdd(fincount, 1) == (int)gridDim.x - 1) {
      out[0] = atomicAdd(&accum[0], 0.f) / (float)NROW;
      out[1] = atomicAdd(&accum[1], 0.f) * 100.f / (float)NROW;
    }
  }
}

// ---------------------------------------------------------------------------
extern "C" void kernel_launch(void* const* d_in, const int* in_sizes, int n_in,
                              void* d_out, int out_size, void* d_ws, size_t ws_size,
                              hipStream_t stream) {
  const float* x     = (const float*)d_in[0];
  const int*   label = (const int*)d_in[1];
  float* out = (float*)d_out;

  // ws layout: [0:2) accum | [2] fincount | [16,16+NCOL) cb |
  // Asw (NCOL*DD ushort) | Qsw (NROW*DD ushort) | partm[8N] | parts[8N] |
  // partbi[8N] | slab[N] | probe scratch (512*256 floats)
  float*  W        = (float*)d_ws;
  float*  accum    = W;
  int*    fincount = (int*)(W + 2);
  float*  cb       = W + 16;
  ushort* Asw      = (ushort*)(cb + NCOL);
  ushort* Qsw      = Asw + (size_t)NCOL * DD;
  float*  partm    = (float*)(Qsw + (size_t)NROW * DD);
  float*  parts    = partm + 8 * NROW;
  int*    partbi   = (int*)(parts + 8 * NROW);
  float*  slabws   = (float*)(partbi + 8 * NROW);
  float*  scratch  = slabws + NROW;

  hipLaunchKernelGGL(proto_prep, dim3(NEP / 4), dim3(256), 0, stream,
                     x, cb, Asw, Qsw, accum, fincount);
  hipLaunchKernelGGL(proto_main, dim3(512), dim3(256), 0, stream,
                     Qsw, Asw, cb, label, partm, parts, partbi, slabws);
  hipLaunchKernelGGL(proto_merge, dim3(NROW / 256), dim3(256), 0, stream,
                     partm, parts, partbi, slabws, label, accum, fincount, out);

  // diagnostic probes (results -> scratch; do not affect out)
  hipLaunchKernelGGL((proto_probe<0, 4>), dim3(512), dim3(256), 0, stream,
                     Qsw, Asw, cb, scratch);
  hipLaunchKernelGGL((proto_probe<1, 4>), dim3(512), dim3(256), 0, stream,
                     Qsw, Asw, cb, scratch);
  hipLaunchKernelGGL((proto_probe<2, 4>), dim3(512), dim3(256), 0, stream,
                     Qsw, Asw, cb, scratch);
  hipLaunchKernelGGL((proto_probe<3, 4>), dim3(512), dim3(256), 0, stream,
                     Qsw, Asw, cb, scratch);
}

// Round 15
// 123.302 us; speedup vs baseline: 2.8717x; 2.8717x over previous
//
#include <hip/hip_runtime.h>
#include <math.h>

#define EPS  1e-6f
#define DD   256
#define NSUP 5
#define NQ   8
#define SEQ  13
#define L2E  1.44269504088896f
#define LN2  0.693147180559945f
#define NEP  2048            // episodes
#define NROW 16384           // NEP*NQ query rows
#define NCOL 2048            // anchor columns

typedef short bf16x8 __attribute__((ext_vector_type(8)));
typedef unsigned short u16x4 __attribute__((ext_vector_type(4)));
typedef float f32x4  __attribute__((ext_vector_type(4)));

__device__ __forceinline__ ushort f2bf(float f) {
  union { float f; unsigned u; } v; v.f = f;
  unsigned r = v.u + 0x7FFFu + ((v.u >> 16) & 1u);   // round-to-nearest-even
  return (ushort)(r >> 16);
}
__device__ __forceinline__ float bf2f(short u) {
  union { unsigned u; float f; } v; v.u = ((unsigned)(unsigned short)u) << 16;
  return v.f;
}

// ---------------------------------------------------------------------------
// prep (r8-proven, unchanged)
// ---------------------------------------------------------------------------
__global__ __launch_bounds__(256) void proto_prep(
    const float* __restrict__ x, float* __restrict__ cb,
    ushort* __restrict__ Asw, ushort* __restrict__ Qsw,
    float* __restrict__ accum, int* __restrict__ fincount) {
  const int tid = threadIdx.x, g = tid >> 6, l = tid & 63;
  const int n = blockIdx.x * 4 + g;
  if (blockIdx.x == 0 && tid == 0) { accum[0] = 0.f; accum[1] = 0.f; fincount[0] = 0; }

  const float4* xr4 = (const float4*)(x + (size_t)n * SEQ * DD);

  const int d0   = l * 4;
  const int kk   = d0 >> 5, quad = (d0 >> 3) & 3, j = d0 & 7;   // j in {0,4}
  const size_t chunk_d = (size_t)kk * 64 + (size_t)quad * 16;

  float4 a = {0.f, 0.f, 0.f, 0.f};
  #pragma unroll
  for (int s = 0; s < NSUP; ++s) {
    float4 v = xr4[s * 64 + l];
    a.x += v.x; a.y += v.y; a.z += v.z; a.w += v.w;
  }
  a.x *= 0.2f; a.y *= 0.2f; a.z *= 0.2f; a.w *= 0.2f;
  {
    const size_t idx = (((size_t)(n >> 4) * 8) * 64 + chunk_d + (n & 15)) * 8 + j;
    u16x4 o = {f2bf(a.x), f2bf(a.y), f2bf(a.z), f2bf(a.w)};
    *(u16x4*)(Asw + idx) = o;
  }
  float s1 = a.x + a.y + a.z + a.w;
  float s2 = a.x * a.x + a.y * a.y + a.z * a.z + a.w * a.w;
  #pragma unroll
  for (int off = 32; off; off >>= 1) {
    s1 += __shfl_xor(s1, off);
    s2 += __shfl_xor(s2, off);
  }
  if (l == 0) cb[n] = -L2E * (s2 - 2.f * EPS * s1);

  #pragma unroll
  for (int s = 0; s < NQ; ++s) {
    float4 q = xr4[(NSUP + s) * 64 + l];
    const int row = n * NQ + s;
    const size_t idx = (((size_t)(row >> 4) * 8) * 64 + chunk_d + (row & 15)) * 8 + j;
    u16x4 o = {f2bf(q.x), f2bf(q.y), f2bf(q.z), f2bf(q.w)};
    *(u16x4*)(Qsw + idx) = o;
  }
}

// ---------------------------------------------------------------------------
// main r27: PROBE-FORM LOOP + COUNTED-VMCNT RING. r26's ablation measured
// steady-state per-tile ~1.5 us in the probe's loop form (112.6 us / 4 reps)
// vs main's 44 = S(~15) + 16T(~24.5 int.) + E(~5), and exposed r25's ~2 MB
// spill (WRITE 3648 vs 1664 real) which the probe's bfr-preload form avoids
// (VGPR 120 + af in AGPRs fits the 256-reg unified budget at (256,2)).
// Changes: (1) probe loop form — one tile per barrier, ring staging, bfr
// register preload; (2) T4 counted vmcnt + raw s_barrier — now CLEAN: zero
// global loads in the loop (sCb in LDS; r17's confound was the in-loop cb
// load). Ring of 4 bufs, stage depth 3: per step stage(t+3 -> buf (t+3)&3),
// compute(t from buf t&3), s_waitcnt vmcnt(4), s_barrier. vmcnt(4) leaves
// only tiles t+2,t+3 in flight -> tile t+1 landed (per-wave FIFO) BEFORE the
// barrier every step; staging has 3 intervals to cover L2/L3 latency instead
// of a full drain per step. Race-audit: stage(t+3) overwrites buf (t-1)&3 —
// every wave's reads of tile t-1 are register-preloaded (lgkmcnt drained at
// use) before it reaches the step t-1 barrier; stage is issued after that
// barrier -> safe. Cross-wave visibility of tile t: each wave's own stages
// proven landed by ITS vmcnt(4) before ITS barrier arrival -> after barrier
// all staged data visible. Tail steps stage wrapped tiles (dummy, probe-
// proven) keeping the FIFO count uniform. Compute order t=0..15 ascending,
// identical slot updates -> BIT-IDENTICAL output (absmax 0 expected).
// Structure otherwise r25: 512 blocks x 256 thr (2 blocks/CU), 256x256
// tile, sets=4, XCD swizzle (blk&63 = rb), direct partials, 8-way merge.
// LDS: Bl[4] 32K + sCb 1K = 33 KB/block. GATES: WRITE ~1.66 MB (no spill),
// FETCH ~8.4 MB, VGPR ~120.
// MFMA layouts (verified): A m=lane&15,k=quad*8+j ; B n=lane&15,k=quad*8+j ;
// C col=lane&15,row=quad*4+reg.
// ---------------------------------------------------------------------------
__global__ __launch_bounds__(256, 2) void proto_main(
    const ushort* __restrict__ Qsw, const ushort* __restrict__ Asw,
    const float* __restrict__ cb, const int* __restrict__ label,
    float* __restrict__ partm, float* __restrict__ parts,
    int* __restrict__ partbi, float* __restrict__ slabws) {
  const int tid  = threadIdx.x;
  const int rowg = tid >> 6, lane = tid & 63;
  const int quad = lane >> 4, lcol = lane & 15;
  const int rb   = blockIdx.x & 63;                 // row-block (256 rows)
  const int colc = blockIdx.x >> 6;                 // col-chunk (256 cols)
  const int r0   = rb * 256;

  const bf16x8* qb = (const bf16x8*)Qsw;
  const bf16x8* bb = (const bf16x8*)Asw;

  __shared__ bf16x8 Bl[4][8][64];                    // 32 KiB, 4-deep ring
  __shared__ float  sCb[256];                        // this chunk's col consts

  sCb[tid] = cb[colc * 256 + tid];                   // one-time, coalesced

  // resident A fragments: 64 rows (4 sets) x 8 K-chunks (AGPR-backed, r26)
  bf16x8 af[4][8];
  #pragma unroll
  for (int set = 0; set < 4; ++set) {
    const size_t base = ((size_t)(rb * 16 + rowg * 4 + set) * 8) * 64 + lane;
    #pragma unroll
    for (int kk = 0; kk < 8; ++kk) af[set][kk] = qb[base + (size_t)kk * 64];
  }

  float m[4][4], s[4][4];
  int   bi[4][4];
  #pragma unroll
  for (int set = 0; set < 4; ++set)
    #pragma unroll
    for (int i = 0; i < 4; ++i) {
      m[set][i] = -1e30f; s[set][i] = 0.f; bi[set][i] = 0x7fffffff;
    }

  // wave (rowg) stages K-chunks {2*rowg, 2*rowg+1} of (ring) tile tl:
  // 2 x global_load_lds width=16 (linear dest). [G13/T3]
  const int kk0 = rowg * 2;
  auto stageT = [&](int tl) {
    const int rt = tl & 15;                          // wrapped tile (tail dummy)
    const int T  = colc * 16 + rt;
    #pragma unroll
    for (int k2 = 0; k2 < 2; ++k2) {
      const int kk = kk0 + k2;
      const ushort* src = Asw + (((size_t)T * 8 + kk) * 64 + lane) * 8;
      __builtin_amdgcn_global_load_lds(
          (const __attribute__((address_space(1))) void*)src,
          (__attribute__((address_space(3))) void*)&Bl[tl & 3][kk][0],
          16, 0, 0);
    }
  };

  stageT(0); stageT(1); stageT(2);                   // 3-deep prologue
  // drain af + cb-load + tile 0 (vmcnt<=4 leaves tiles 1,2); lgkm covers sCb
  asm volatile("s_waitcnt vmcnt(4) lgkmcnt(0)" ::: "memory");
  __builtin_amdgcn_s_barrier();

  #pragma unroll 1
  for (int t = 0; t < 16; ++t) {
    stageT(t + 3);                                   // into buf (t+3)&3
    // compute tile t from buf t&3 (probe-form: register preload then MFMA)
    bf16x8 bfr[8];
    #pragma unroll
    for (int kk = 0; kk < 8; ++kk) bfr[kk] = Bl[t & 3][kk][lane];
    f32x4 c0 = {0.f, 0.f, 0.f, 0.f}, c1 = {0.f, 0.f, 0.f, 0.f};
    f32x4 c2 = {0.f, 0.f, 0.f, 0.f}, c3 = {0.f, 0.f, 0.f, 0.f};
    #pragma unroll
    for (int kk = 0; kk < 8; ++kk) {
      c0 = __builtin_amdgcn_mfma_f32_16x16x32_bf16(af[0][kk], bfr[kk], c0, 0, 0, 0);
      c1 = __builtin_amdgcn_mfma_f32_16x16x32_bf16(af[1][kk], bfr[kk], c1, 0, 0, 0);
      c2 = __builtin_amdgcn_mfma_f32_16x16x32_bf16(af[2][kk], bfr[kk], c2, 0, 0, 0);
      c3 = __builtin_amdgcn_mfma_f32_16x16x32_bf16(af[3][kk], bfr[kk], c3, 0, 0, 0);
    }
    const int   lcIdx  = t * 16 + lcol;
    const int   colIdx = colc * 256 + lcIdx;
    const float cbv    = sCb[lcIdx];                 // LDS broadcast
    #pragma unroll
    for (int set = 0; set < 4; ++set) {
      #pragma unroll
      for (int i = 0; i < 4; ++i) {
        float cv = (set == 0) ? c0[i] : (set == 1) ? c1[i]
                 : (set == 2) ? c2[i] : c3[i];
        float v2 = fmaf(cv, 2.f * L2E, cbv);         // log2-frame shifted logit
        float dv = v2 - m[set][i];
        bool  gt = dv > 0.f;
        float e  = exp2f(-fabsf(dv));                // single non-unit exp factor
        s[set][i]  = fmaf(s[set][i], gt ? e : 1.f, gt ? 1.f : e);
        m[set][i]  = fmaxf(m[set][i], v2);
        bi[set][i] = gt ? colIdx : bi[set][i];       // strict >: first max wins
      }
    }
    // counted wait: <=4 outstanding (tiles t+2,t+3) -> tile t+1 landed;
    // raw barrier publishes WITHOUT draining in-flight staging. [T4]
    asm volatile("s_waitcnt vmcnt(4)" ::: "memory");
    __builtin_amdgcn_s_barrier();
  }

  // merge across the 16 lanes sharing rows (cols differ); rows unique to
  // this wave -> lcol==0 lanes hold final per-row partials.
  #pragma unroll
  for (int mask = 1; mask < 16; mask <<= 1) {
    #pragma unroll
    for (int set = 0; set < 4; ++set)
      #pragma unroll
      for (int i = 0; i < 4; ++i) {
        float om = __shfl_xor(m[set][i], mask);
        float os = __shfl_xor(s[set][i], mask);
        int   oi = __shfl_xor(bi[set][i], mask);
        float nm = fmaxf(m[set][i], om);
        s[set][i] = s[set][i] * exp2f(m[set][i] - nm) + os * exp2f(om - nm);
        bool better = (om > m[set][i]) || (om == m[set][i] && oi < bi[set][i]);
        bi[set][i] = better ? oi : bi[set][i];
        m[set][i]  = nm;
      }
  }

  if (lcol == 0) {                                   // direct partials write
    #pragma unroll
    for (int set = 0; set < 4; ++set)
      #pragma unroll
      for (int i = 0; i < 4; ++i) {
        const int row = r0 + rowg * 64 + set * 16 + quad * 4 + i;
        partm [colc * NROW + row] = m[set][i];
        parts [colc * NROW + row] = s[set][i];
        partbi[colc * NROW + row] = bi[set][i];
      }
  }

  // label-logit pass (r11-proven dot), colc==0 blocks only: 1 thread/row.
  if (colc == 0) {
    const int row = r0 + tid;
    const int lab = label[row >> 3];
    float dot = 0.f;
    #pragma unroll
    for (int kk = 0; kk < 8; ++kk) {
      const size_t qc = ((size_t)(row >> 4) * 8 + kk) * 64 + (row & 15);
      const size_t ac = ((size_t)(lab >> 4) * 8 + kk) * 64 + (lab & 15);
      #pragma unroll
      for (int qd = 0; qd < 4; ++qd) {
        bf16x8 qv = qb[qc + qd * 16];
        bf16x8 av = bb[ac + qd * 16];
        #pragma unroll
        for (int j = 0; j < 8; ++j) dot = fmaf(bf2f(qv[j]), bf2f(av[j]), dot);
      }
    }
    slabws[row] = fmaf(dot, 2.f * L2E, cb[lab]);
  }
}

// ---------------------------------------------------------------------------
// merge (r25, unchanged): 8-way chunk merge + loss/prec1 finalize.
// ---------------------------------------------------------------------------
__global__ __launch_bounds__(256) void proto_merge(
    const float* __restrict__ partm, const float* __restrict__ parts,
    const int* __restrict__ partbi, const float* __restrict__ slabws,
    const int* __restrict__ label,
    float* __restrict__ accum, int* __restrict__ fincount,
    float* __restrict__ out) {
  const int tid = threadIdx.x, row = blockIdx.x * 256 + tid;
  const int wid = tid >> 6;

  float mm = partm[row], sv = parts[row];
  int   b  = partbi[row];
  #pragma unroll
  for (int c = 1; c < 8; ++c) {                      // chunks in ascending cols
    float om = partm[c * NROW + row], os = parts[c * NROW + row];
    int   oi = partbi[c * NROW + row];
    float nm = fmaxf(mm, om);
    sv = sv * exp2f(mm - nm) + os * exp2f(om - nm);
    bool better = (om > mm) || (om == mm && oi < b);
    b = better ? oi : b;
    mm = nm;
  }

  const int lb = label[row >> 3];
  float loss = LN2 * (mm + log2f(sv) - slabws[row]);
  float corr = (b == lb) ? 1.f : 0.f;

  #pragma unroll
  for (int mask = 32; mask; mask >>= 1) {
    loss += __shfl_xor(loss, mask);
    corr += __shfl_xor(corr, mask);
  }
  __shared__ float red[2][4];
  if ((tid & 63) == 0) { red[0][wid] = loss; red[1][wid] = corr; }
  __syncthreads();
  if (tid == 0) {
    float L = red[0][0] + red[0][1] + red[0][2] + red[0][3];
    float C = red[1][0] + red[1][1] + red[1][2] + red[1][3];
    atomicAdd(&accum[0], L);
    atomicAdd(&accum[1], C);
    __threadfence();
    if (atomicAdd(fincount, 1) == (int)gridDim.x - 1) {
      out[0] = atomicAdd(&accum[0], 0.f) / (float)NROW;     // coherent reads
      out[1] = atomicAdd(&accum[1], 0.f) * 100.f / (float)NROW;
    }
  }
}

// ---------------------------------------------------------------------------
extern "C" void kernel_launch(void* const* d_in, const int* in_sizes, int n_in,
                              void* d_out, int out_size, void* d_ws, size_t ws_size,
                              hipStream_t stream) {
  const float* x     = (const float*)d_in[0];
  const int*   label = (const int*)d_in[1];
  float* out = (float*)d_out;

  // ws layout: [0:2) accum | [2] fincount | [16,16+NCOL) cb |
  // Asw (NCOL*DD ushort) | Qsw (NROW*DD ushort) | partm[8N] | parts[8N] |
  // partbi[8N] | slab[N]  (~1.7 MB)
  float*  W        = (float*)d_ws;
  float*  accum    = W;
  int*    fincount = (int*)(W + 2);
  float*  cb       = W + 16;
  ushort* Asw      = (ushort*)(cb + NCOL);
  ushort* Qsw      = Asw + (size_t)NCOL * DD;
  float*  partm    = (float*)(Qsw + (size_t)NROW * DD);
  float*  parts    = partm + 8 * NROW;
  int*    partbi   = (int*)(parts + 8 * NROW);
  float*  slabws   = (float*)(partbi + 8 * NROW);

  hipLaunchKernelGGL(proto_prep, dim3(NEP / 4), dim3(256), 0, stream,
                     x, cb, Asw, Qsw, accum, fincount);
  hipLaunchKernelGGL(proto_main, dim3(512), dim3(256), 0, stream,
                     Qsw, Asw, cb, label, partm, parts, partbi, slabws);
  hipLaunchKernelGGL(proto_merge, dim3(NROW / 256), dim3(256), 0, stream,
                     partm, parts, partbi, slabws, label, accum, fincount, out);
}

// Round 16
// 118.714 us; speedup vs baseline: 2.9827x; 1.0386x over previous
//
#include <hip/hip_runtime.h>
#include <math.h>

#define EPS  1e-6f
#define DD   256
#define NSUP 5
#define NQ   8
#define SEQ  13
#define L2E  1.44269504088896f
#define LN2  0.693147180559945f
#define NEP  2048            // episodes
#define NROW 16384           // NEP*NQ query rows
#define NCOL 2048            // anchor columns

typedef short bf16x8 __attribute__((ext_vector_type(8)));
typedef unsigned short u16x4 __attribute__((ext_vector_type(4)));
typedef float f32x4  __attribute__((ext_vector_type(4)));

__device__ __forceinline__ ushort f2bf(float f) {
  union { float f; unsigned u; } v; v.f = f;
  unsigned r = v.u + 0x7FFFu + ((v.u >> 16) & 1u);   // round-to-nearest-even
  return (ushort)(r >> 16);
}
__device__ __forceinline__ float bf2f(short u) {
  union { unsigned u; float f; } v; v.u = ((unsigned)(unsigned short)u) << 16;
  return v.f;
}

// ---------------------------------------------------------------------------
// prep (r8-proven, unchanged)
// ---------------------------------------------------------------------------
__global__ __launch_bounds__(256) void proto_prep(
    const float* __restrict__ x, float* __restrict__ cb,
    ushort* __restrict__ Asw, ushort* __restrict__ Qsw,
    float* __restrict__ accum, int* __restrict__ fincount) {
  const int tid = threadIdx.x, g = tid >> 6, l = tid & 63;
  const int n = blockIdx.x * 4 + g;
  if (blockIdx.x == 0 && tid == 0) { accum[0] = 0.f; accum[1] = 0.f; fincount[0] = 0; }

  const float4* xr4 = (const float4*)(x + (size_t)n * SEQ * DD);

  const int d0   = l * 4;
  const int kk   = d0 >> 5, quad = (d0 >> 3) & 3, j = d0 & 7;   // j in {0,4}
  const size_t chunk_d = (size_t)kk * 64 + (size_t)quad * 16;

  float4 a = {0.f, 0.f, 0.f, 0.f};
  #pragma unroll
  for (int s = 0; s < NSUP; ++s) {
    float4 v = xr4[s * 64 + l];
    a.x += v.x; a.y += v.y; a.z += v.z; a.w += v.w;
  }
  a.x *= 0.2f; a.y *= 0.2f; a.z *= 0.2f; a.w *= 0.2f;
  {
    const size_t idx = (((size_t)(n >> 4) * 8) * 64 + chunk_d + (n & 15)) * 8 + j;
    u16x4 o = {f2bf(a.x), f2bf(a.y), f2bf(a.z), f2bf(a.w)};
    *(u16x4*)(Asw + idx) = o;
  }
  float s1 = a.x + a.y + a.z + a.w;
  float s2 = a.x * a.x + a.y * a.y + a.z * a.z + a.w * a.w;
  #pragma unroll
  for (int off = 32; off; off >>= 1) {
    s1 += __shfl_xor(s1, off);
    s2 += __shfl_xor(s2, off);
  }
  if (l == 0) cb[n] = -L2E * (s2 - 2.f * EPS * s1);

  #pragma unroll
  for (int s = 0; s < NQ; ++s) {
    float4 q = xr4[(NSUP + s) * 64 + l];
    const int row = n * NQ + s;
    const size_t idx = (((size_t)(row >> 4) * 8) * 64 + chunk_d + (row & 15)) * 8 + j;
    u16x4 o = {f2bf(q.x), f2bf(q.y), f2bf(q.z), f2bf(q.w)};
    *(u16x4*)(Qsw + idx) = o;
  }
}

// ---------------------------------------------------------------------------
// main r28: PAIRED INTERVALS (8 barriers, 6-buf ring). r27's counted-vmcnt
// ring verified bit-exact (absmax 0.0) and pushed main below all ~44 us
// poison fills (out of rocprof top-5). Remaining per-tile overhead is the
// wait+barrier rendezvous itself (16/block); this round halves it: process
// 2 tiles per interval. Ring of 6 bufs (tile t -> buf t%6, 48K+1K LDS,
// 2 blocks/CU = 100K <= 160K). Per step s: stage pair s+2 (tiles 2s+4,
// 2s+5 -> 4 loads), compute tile 2s, compute tile 2s+1 (sequential: same
// register peak as r27), s_waitcnt vmcnt(4) -> only pair s+2's 4 loads
// outstanding => pair s+1 LANDED (per-wave FIFO) before the barrier; raw
// s_barrier publishes without draining. Staging latency window doubles to
// 2 intervals. Tail: steps 6,7 stage wrapped tiles 16..19 (dummy) into
// bufs 4,5,0,1 which hold tiles consumed 2 steps earlier — safe (audited).
// Compute order t=0..15 ascending, identical updates -> BIT-IDENTICAL
// output. Structure otherwise r27: 512 blocks x 256 thr (2 blocks/CU),
// 256x256 tile, sets=4 (af AGPR-backed), XCD swizzle (rb=blk&63), sCb in
// LDS, direct partials, 8-way merge kernel.
// GATES: absmax 0.0, WRITE ~1.66 MB, FETCH ~8.4 MB, LDS ~50 KB.
// MFMA layouts (verified): A m=lane&15,k=quad*8+j ; B n=lane&15,k=quad*8+j ;
// C col=lane&15,row=quad*4+reg.
// ---------------------------------------------------------------------------
__global__ __launch_bounds__(256, 2) void proto_main(
    const ushort* __restrict__ Qsw, const ushort* __restrict__ Asw,
    const float* __restrict__ cb, const int* __restrict__ label,
    float* __restrict__ partm, float* __restrict__ parts,
    int* __restrict__ partbi, float* __restrict__ slabws) {
  const int tid  = threadIdx.x;
  const int rowg = tid >> 6, lane = tid & 63;
  const int quad = lane >> 4, lcol = lane & 15;
  const int rb   = blockIdx.x & 63;                 // row-block (256 rows)
  const int colc = blockIdx.x >> 6;                 // col-chunk (256 cols)
  const int r0   = rb * 256;

  const bf16x8* qb = (const bf16x8*)Qsw;
  const bf16x8* bb = (const bf16x8*)Asw;

  __shared__ bf16x8 Bl[6][8][64];                    // 48 KiB, 6-deep ring
  __shared__ float  sCb[256];                        // this chunk's col consts

  sCb[tid] = cb[colc * 256 + tid];                   // one-time, coalesced

  // resident A fragments: 64 rows (4 sets) x 8 K-chunks (AGPR-backed, r26)
  bf16x8 af[4][8];
  #pragma unroll
  for (int set = 0; set < 4; ++set) {
    const size_t base = ((size_t)(rb * 16 + rowg * 4 + set) * 8) * 64 + lane;
    #pragma unroll
    for (int kk = 0; kk < 8; ++kk) af[set][kk] = qb[base + (size_t)kk * 64];
  }

  float m[4][4], s[4][4];
  int   bi[4][4];
  #pragma unroll
  for (int set = 0; set < 4; ++set)
    #pragma unroll
    for (int i = 0; i < 4; ++i) {
      m[set][i] = -1e30f; s[set][i] = 0.f; bi[set][i] = 0x7fffffff;
    }

  // wave (rowg) stages K-chunks {2*rowg, 2*rowg+1} of tile tl -> buf tl%6:
  // 2 x global_load_lds width=16 (linear dest). [G13/T3]
  const int kk0 = rowg * 2;
  auto stageT = [&](int tl) {
    const int rt = tl & 15;                          // wrapped tile (tail dummy)
    const int T  = colc * 16 + rt;
    const int bidx = tl % 6;
    #pragma unroll
    for (int k2 = 0; k2 < 2; ++k2) {
      const int kk = kk0 + k2;
      const ushort* src = Asw + (((size_t)T * 8 + kk) * 64 + lane) * 8;
      __builtin_amdgcn_global_load_lds(
          (const __attribute__((address_space(1))) void*)src,
          (__attribute__((address_space(3))) void*)&Bl[bidx][kk][0],
          16, 0, 0);
    }
  };

  // one full tile: register preload -> 32 MFMA -> 16 slot updates
  auto computeT = [&](int t) {
    bf16x8 bfr[8];
    const int bidx = t % 6;
    #pragma unroll
    for (int kk = 0; kk < 8; ++kk) bfr[kk] = Bl[bidx][kk][lane];
    f32x4 c0 = {0.f, 0.f, 0.f, 0.f}, c1 = {0.f, 0.f, 0.f, 0.f};
    f32x4 c2 = {0.f, 0.f, 0.f, 0.f}, c3 = {0.f, 0.f, 0.f, 0.f};
    #pragma unroll
    for (int kk = 0; kk < 8; ++kk) {
      c0 = __builtin_amdgcn_mfma_f32_16x16x32_bf16(af[0][kk], bfr[kk], c0, 0, 0, 0);
      c1 = __builtin_amdgcn_mfma_f32_16x16x32_bf16(af[1][kk], bfr[kk], c1, 0, 0, 0);
      c2 = __builtin_amdgcn_mfma_f32_16x16x32_bf16(af[2][kk], bfr[kk], c2, 0, 0, 0);
      c3 = __builtin_amdgcn_mfma_f32_16x16x32_bf16(af[3][kk], bfr[kk], c3, 0, 0, 0);
    }
    const int   lcIdx  = t * 16 + lcol;
    const int   colIdx = colc * 256 + lcIdx;
    const float cbv    = sCb[lcIdx];                 // LDS broadcast
    #pragma unroll
    for (int set = 0; set < 4; ++set) {
      #pragma unroll
      for (int i = 0; i < 4; ++i) {
        float cv = (set == 0) ? c0[i] : (set == 1) ? c1[i]
                 : (set == 2) ? c2[i] : c3[i];
        float v2 = fmaf(cv, 2.f * L2E, cbv);         // log2-frame shifted logit
        float dv = v2 - m[set][i];
        bool  gt = dv > 0.f;
        float e  = exp2f(-fabsf(dv));                // single non-unit exp factor
        s[set][i]  = fmaf(s[set][i], gt ? e : 1.f, gt ? 1.f : e);
        m[set][i]  = fmaxf(m[set][i], v2);
        bi[set][i] = gt ? colIdx : bi[set][i];       // strict >: first max wins
      }
    }
  };

  stageT(0); stageT(1); stageT(2); stageT(3);        // pairs 0,1 (8 loads)
  // wait until <=4 outstanding: pair 0 landed, pair 1 in flight; sCb via lgkm
  asm volatile("s_waitcnt vmcnt(4) lgkmcnt(0)" ::: "memory");
  __builtin_amdgcn_s_barrier();

  #pragma unroll 1
  for (int st = 0; st < 8; ++st) {
    stageT(2 * st + 4);                              // pair st+2 (4 loads)
    stageT(2 * st + 5);
    computeT(2 * st);
    computeT(2 * st + 1);
    // <=4 outstanding = pair st+2's loads -> pair st+1 landed (FIFO). [T4]
    asm volatile("s_waitcnt vmcnt(4)" ::: "memory");
    __builtin_amdgcn_s_barrier();
  }

  // merge across the 16 lanes sharing rows (cols differ); rows unique to
  // this wave -> lcol==0 lanes hold final per-row partials.
  #pragma unroll
  for (int mask = 1; mask < 16; mask <<= 1) {
    #pragma unroll
    for (int set = 0; set < 4; ++set)
      #pragma unroll
      for (int i = 0; i < 4; ++i) {
        float om = __shfl_xor(m[set][i], mask);
        float os = __shfl_xor(s[set][i], mask);
        int   oi = __shfl_xor(bi[set][i], mask);
        float nm = fmaxf(m[set][i], om);
        s[set][i] = s[set][i] * exp2f(m[set][i] - nm) + os * exp2f(om - nm);
        bool better = (om > m[set][i]) || (om == m[set][i] && oi < bi[set][i]);
        bi[set][i] = better ? oi : bi[set][i];
        m[set][i]  = nm;
      }
  }

  if (lcol == 0) {                                   // direct partials write
    #pragma unroll
    for (int set = 0; set < 4; ++set)
      #pragma unroll
      for (int i = 0; i < 4; ++i) {
        const int row = r0 + rowg * 64 + set * 16 + quad * 4 + i;
        partm [colc * NROW + row] = m[set][i];
        parts [colc * NROW + row] = s[set][i];
        partbi[colc * NROW + row] = bi[set][i];
      }
  }

  // label-logit pass (r11-proven dot), colc==0 blocks only: 1 thread/row.
  if (colc == 0) {
    const int row = r0 + tid;
    const int lab = label[row >> 3];
    float dot = 0.f;
    #pragma unroll
    for (int kk = 0; kk < 8; ++kk) {
      const size_t qc = ((size_t)(row >> 4) * 8 + kk) * 64 + (row & 15);
      const size_t ac = ((size_t)(lab >> 4) * 8 + kk) * 64 + (lab & 15);
      #pragma unroll
      for (int qd = 0; qd < 4; ++qd) {
        bf16x8 qv = qb[qc + qd * 16];
        bf16x8 av = bb[ac + qd * 16];
        #pragma unroll
        for (int j = 0; j < 8; ++j) dot = fmaf(bf2f(qv[j]), bf2f(av[j]), dot);
      }
    }
    slabws[row] = fmaf(dot, 2.f * L2E, cb[lab]);
  }
}

// ---------------------------------------------------------------------------
// merge (r25, unchanged): 8-way chunk merge + loss/prec1 finalize.
// ---------------------------------------------------------------------------
__global__ __launch_bounds__(256) void proto_merge(
    const float* __restrict__ partm, const float* __restrict__ parts,
    const int* __restrict__ partbi, const float* __restrict__ slabws,
    const int* __restrict__ label,
    float* __restrict__ accum, int* __restrict__ fincount,
    float* __restrict__ out) {
  const int tid = threadIdx.x, row = blockIdx.x * 256 + tid;
  const int wid = tid >> 6;

  float mm = partm[row], sv = parts[row];
  int   b  = partbi[row];
  #pragma unroll
  for (int c = 1; c < 8; ++c) {                      // chunks in ascending cols
    float om = partm[c * NROW + row], os = parts[c * NROW + row];
    int   oi = partbi[c * NROW + row];
    float nm = fmaxf(mm, om);
    sv = sv * exp2f(mm - nm) + os * exp2f(om - nm);
    bool better = (om > mm) || (om == mm && oi < b);
    b = better ? oi : b;
    mm = nm;
  }

  const int lb = label[row >> 3];
  float loss = LN2 * (mm + log2f(sv) - slabws[row]);
  float corr = (b == lb) ? 1.f : 0.f;

  #pragma unroll
  for (int mask = 32; mask; mask >>= 1) {
    loss += __shfl_xor(loss, mask);
    corr += __shfl_xor(corr, mask);
  }
  __shared__ float red[2][4];
  if ((tid & 63) == 0) { red[0][wid] = loss; red[1][wid] = corr; }
  __syncthreads();
  if (tid == 0) {
    float L = red[0][0] + red[0][1] + red[0][2] + red[0][3];
    float C = red[1][0] + red[1][1] + red[1][2] + red[1][3];
    atomicAdd(&accum[0], L);
    atomicAdd(&accum[1], C);
    __threadfence();
    if (atomicAdd(fincount, 1) == (int)gridDim.x - 1) {
      out[0] = atomicAdd(&accum[0], 0.f) / (float)NROW;     // coherent reads
      out[1] = atomicAdd(&accum[1], 0.f) * 100.f / (float)NROW;
    }
  }
}

// ---------------------------------------------------------------------------
extern "C" void kernel_launch(void* const* d_in, const int* in_sizes, int n_in,
                              void* d_out, int out_size, void* d_ws, size_t ws_size,
                              hipStream_t stream) {
  const float* x     = (const float*)d_in[0];
  const int*   label = (const int*)d_in[1];
  float* out = (float*)d_out;

  // ws layout: [0:2) accum | [2] fincount | [16,16+NCOL) cb |
  // Asw (NCOL*DD ushort) | Qsw (NROW*DD ushort) | partm[8N] | parts[8N] |
  // partbi[8N] | slab[N]  (~1.7 MB)
  float*  W        = (float*)d_ws;
  float*  accum    = W;
  int*    fincount = (int*)(W + 2);
  float*  cb       = W + 16;
  ushort* Asw      = (ushort*)(cb + NCOL);
  ushort* Qsw      = Asw + (size_t)NCOL * DD;
  float*  partm    = (float*)(Qsw + (size_t)NROW * DD);
  float*  parts    = partm + 8 * NROW;
  int*    partbi   = (int*)(parts + 8 * NROW);
  float*  slabws   = (float*)(partbi + 8 * NROW);

  hipLaunchKernelGGL(proto_prep, dim3(NEP / 4), dim3(256), 0, stream,
                     x, cb, Asw, Qsw, accum, fincount);
  hipLaunchKernelGGL(proto_main, dim3(512), dim3(256), 0, stream,
                     Qsw, Asw, cb, label, partm, parts, partbi, slabws);
  hipLaunchKernelGGL(proto_merge, dim3(NROW / 256), dim3(256), 0, stream,
                     partm, parts, partbi, slabws, label, accum, fincount, out);
}

// Round 18
// 118.596 us; speedup vs baseline: 2.9856x; 1.0010x over previous
//
#include <hip/hip_runtime.h>
#include <math.h>

#define EPS  1e-6f
#define DD   256
#define NSUP 5
#define NQ   8
#define SEQ  13
#define L2E  1.44269504088896f
#define LN2  0.693147180559945f
#define NEP  2048            // episodes
#define NROW 16384           // NEP*NQ query rows
#define NCOL 2048            // anchor columns

typedef short bf16x8 __attribute__((ext_vector_type(8)));
typedef unsigned short u16x4 __attribute__((ext_vector_type(4)));
typedef float f32x4  __attribute__((ext_vector_type(4)));

__device__ __forceinline__ ushort f2bf(float f) {
  union { float f; unsigned u; } v; v.f = f;
  unsigned r = v.u + 0x7FFFu + ((v.u >> 16) & 1u);   // round-to-nearest-even
  return (ushort)(r >> 16);
}
__device__ __forceinline__ float bf2f(short u) {
  union { unsigned u; float f; } v; v.u = ((unsigned)(unsigned short)u) << 16;
  return v.f;
}

// ---------------------------------------------------------------------------
// prep (r8-proven, unchanged)
// ---------------------------------------------------------------------------
__global__ __launch_bounds__(256) void proto_prep(
    const float* __restrict__ x, float* __restrict__ cb,
    ushort* __restrict__ Asw, ushort* __restrict__ Qsw,
    float* __restrict__ accum, int* __restrict__ fincount) {
  const int tid = threadIdx.x, g = tid >> 6, l = tid & 63;
  const int n = blockIdx.x * 4 + g;
  if (blockIdx.x == 0 && tid == 0) { accum[0] = 0.f; accum[1] = 0.f; fincount[0] = 0; }

  const float4* xr4 = (const float4*)(x + (size_t)n * SEQ * DD);

  const int d0   = l * 4;
  const int kk   = d0 >> 5, quad = (d0 >> 3) & 3, j = d0 & 7;   // j in {0,4}
  const size_t chunk_d = (size_t)kk * 64 + (size_t)quad * 16;

  float4 a = {0.f, 0.f, 0.f, 0.f};
  #pragma unroll
  for (int s = 0; s < NSUP; ++s) {
    float4 v = xr4[s * 64 + l];
    a.x += v.x; a.y += v.y; a.z += v.z; a.w += v.w;
  }
  a.x *= 0.2f; a.y *= 0.2f; a.z *= 0.2f; a.w *= 0.2f;
  {
    const size_t idx = (((size_t)(n >> 4) * 8) * 64 + chunk_d + (n & 15)) * 8 + j;
    u16x4 o = {f2bf(a.x), f2bf(a.y), f2bf(a.z), f2bf(a.w)};
    *(u16x4*)(Asw + idx) = o;
  }
  float s1 = a.x + a.y + a.z + a.w;
  float s2 = a.x * a.x + a.y * a.y + a.z * a.z + a.w * a.w;
  #pragma unroll
  for (int off = 32; off; off >>= 1) {
    s1 += __shfl_xor(s1, off);
    s2 += __shfl_xor(s2, off);
  }
  if (l == 0) cb[n] = -L2E * (s2 - 2.f * EPS * s1);

  #pragma unroll
  for (int s = 0; s < NQ; ++s) {
    float4 q = xr4[(NSUP + s) * 64 + l];
    const int row = n * NQ + s;
    const size_t idx = (((size_t)(row >> 4) * 8) * 64 + chunk_d + (row & 15)) * 8 + j;
    u16x4 o = {f2bf(q.x), f2bf(q.y), f2bf(q.z), f2bf(q.w)};
    *(u16x4*)(Qsw + idx) = o;
  }
}

// ---------------------------------------------------------------------------
// main r28 (VERIFIED BEST, reverted from failed r29 fusion): paired counted-
// vmcnt ring. r29's cooperative fusion failed (absmax ~50: either coop
// launch no-op under graph capture, or phase-1 outputs stale cross-XCD —
// the kernel-boundary L2 flush was load-bearing). 3-dispatch structure is
// retained as correctness-required.
// Structure: 512 blocks x 256 thr (2 blocks/CU), 256x256 tile, sets=4
// (af AGPR-backed), XCD swizzle (rb=blk&63 -> A-siblings co-XCD), sCb in
// LDS (zero global loads in loop), 6-buf ring, 2 tiles/interval, 8 raw
// barriers with s_waitcnt vmcnt(4) (pair s+1 proven landed by FIFO; pair
// s+2 stays in flight across the barrier). Bit-exact (absmax 0.0, r28).
// MFMA layouts (verified): A m=lane&15,k=quad*8+j ; B n=lane&15,k=quad*8+j ;
// C col=lane&15,row=quad*4+reg.
// ---------------------------------------------------------------------------
__global__ __launch_bounds__(256, 2) void proto_main(
    const ushort* __restrict__ Qsw, const ushort* __restrict__ Asw,
    const float* __restrict__ cb, const int* __restrict__ label,
    float* __restrict__ partm, float* __restrict__ parts,
    int* __restrict__ partbi, float* __restrict__ slabws) {
  const int tid  = threadIdx.x;
  const int rowg = tid >> 6, lane = tid & 63;
  const int quad = lane >> 4, lcol = lane & 15;
  const int rb   = blockIdx.x & 63;                 // row-block (256 rows)
  const int colc = blockIdx.x >> 6;                 // col-chunk (256 cols)
  const int r0   = rb * 256;

  const bf16x8* qb = (const bf16x8*)Qsw;
  const bf16x8* bb = (const bf16x8*)Asw;

  __shared__ bf16x8 Bl[6][8][64];                    // 48 KiB, 6-deep ring
  __shared__ float  sCb[256];                        // this chunk's col consts

  sCb[tid] = cb[colc * 256 + tid];                   // one-time, coalesced

  // resident A fragments: 64 rows (4 sets) x 8 K-chunks (AGPR-backed, r26)
  bf16x8 af[4][8];
  #pragma unroll
  for (int set = 0; set < 4; ++set) {
    const size_t base = ((size_t)(rb * 16 + rowg * 4 + set) * 8) * 64 + lane;
    #pragma unroll
    for (int kk = 0; kk < 8; ++kk) af[set][kk] = qb[base + (size_t)kk * 64];
  }

  float m[4][4], s[4][4];
  int   bi[4][4];
  #pragma unroll
  for (int set = 0; set < 4; ++set)
    #pragma unroll
    for (int i = 0; i < 4; ++i) {
      m[set][i] = -1e30f; s[set][i] = 0.f; bi[set][i] = 0x7fffffff;
    }

  // wave (rowg) stages K-chunks {2*rowg, 2*rowg+1} of tile tl -> buf tl%6:
  // 2 x global_load_lds width=16 (linear dest). [G13/T3]
  const int kk0 = rowg * 2;
  auto stageT = [&](int tl) {
    const int rt = tl & 15;                          // wrapped tile (tail dummy)
    const int T  = colc * 16 + rt;
    const int bidx = tl % 6;
    #pragma unroll
    for (int k2 = 0; k2 < 2; ++k2) {
      const int kk = kk0 + k2;
      const ushort* src = Asw + (((size_t)T * 8 + kk) * 64 + lane) * 8;
      __builtin_amdgcn_global_load_lds(
          (const __attribute__((address_space(1))) void*)src,
          (__attribute__((address_space(3))) void*)&Bl[bidx][kk][0],
          16, 0, 0);
    }
  };

  // one full tile: register preload -> 32 MFMA -> 16 slot updates
  auto computeT = [&](int t) {
    bf16x8 bfr[8];
    const int bidx = t % 6;
    #pragma unroll
    for (int kk = 0; kk < 8; ++kk) bfr[kk] = Bl[bidx][kk][lane];
    f32x4 c0 = {0.f, 0.f, 0.f, 0.f}, c1 = {0.f, 0.f, 0.f, 0.f};
    f32x4 c2 = {0.f, 0.f, 0.f, 0.f}, c3 = {0.f, 0.f, 0.f, 0.f};
    #pragma unroll
    for (int kk = 0; kk < 8; ++kk) {
      c0 = __builtin_amdgcn_mfma_f32_16x16x32_bf16(af[0][kk], bfr[kk], c0, 0, 0, 0);
      c1 = __builtin_amdgcn_mfma_f32_16x16x32_bf16(af[1][kk], bfr[kk], c1, 0, 0, 0);
      c2 = __builtin_amdgcn_mfma_f32_16x16x32_bf16(af[2][kk], bfr[kk], c2, 0, 0, 0);
      c3 = __builtin_amdgcn_mfma_f32_16x16x32_bf16(af[3][kk], bfr[kk], c3, 0, 0, 0);
    }
    const int   lcIdx  = t * 16 + lcol;
    const int   colIdx = colc * 256 + lcIdx;
    const float cbv    = sCb[lcIdx];                 // LDS broadcast
    #pragma unroll
    for (int set = 0; set < 4; ++set) {
      #pragma unroll
      for (int i = 0; i < 4; ++i) {
        float cv = (set == 0) ? c0[i] : (set == 1) ? c1[i]
                 : (set == 2) ? c2[i] : c3[i];
        float v2 = fmaf(cv, 2.f * L2E, cbv);         // log2-frame shifted logit
        float dv = v2 - m[set][i];
        bool  gt = dv > 0.f;
        float e  = exp2f(-fabsf(dv));                // single non-unit exp factor
        s[set][i]  = fmaf(s[set][i], gt ? e : 1.f, gt ? 1.f : e);
        m[set][i]  = fmaxf(m[set][i], v2);
        bi[set][i] = gt ? colIdx : bi[set][i];       // strict >: first max wins
      }
    }
  };

  stageT(0); stageT(1); stageT(2); stageT(3);        // pairs 0,1 (8 loads)
  // wait until <=4 outstanding: pair 0 landed, pair 1 in flight; sCb via lgkm
  asm volatile("s_waitcnt vmcnt(4) lgkmcnt(0)" ::: "memory");
  __builtin_amdgcn_s_barrier();

  #pragma unroll 1
  for (int st = 0; st < 8; ++st) {
    stageT(2 * st + 4);                              // pair st+2 (4 loads)
    stageT(2 * st + 5);
    computeT(2 * st);
    computeT(2 * st + 1);
    // <=4 outstanding = pair st+2's loads -> pair st+1 landed (FIFO). [T4]
    asm volatile("s_waitcnt vmcnt(4)" ::: "memory");
    __builtin_amdgcn_s_barrier();
  }

  // merge across the 16 lanes sharing rows (cols differ); rows unique to
  // this wave -> lcol==0 lanes hold final per-row partials.
  #pragma unroll
  for (int mask = 1; mask < 16; mask <<= 1) {
    #pragma unroll
    for (int set = 0; set < 4; ++set)
      #pragma unroll
      for (int i = 0; i < 4; ++i) {
        float om = __shfl_xor(m[set][i], mask);
        float os = __shfl_xor(s[set][i], mask);
        int   oi = __shfl_xor(bi[set][i], mask);
        float nm = fmaxf(m[set][i], om);
        s[set][i] = s[set][i] * exp2f(m[set][i] - nm) + os * exp2f(om - nm);
        bool better = (om > m[set][i]) || (om == m[set][i] && oi < bi[set][i]);
        bi[set][i] = better ? oi : bi[set][i];
        m[set][i]  = nm;
      }
  }

  if (lcol == 0) {                                   // direct partials write
    #pragma unroll
    for (int set = 0; set < 4; ++set)
      #pragma unroll
      for (int i = 0; i < 4; ++i) {
        const int row = r0 + rowg * 64 + set * 16 + quad * 4 + i;
        partm [colc * NROW + row] = m[set][i];
        parts [colc * NROW + row] = s[set][i];
        partbi[colc * NROW + row] = bi[set][i];
      }
  }

  // label-logit pass (r11-proven dot), colc==0 blocks only: 1 thread/row.
  if (colc == 0) {
    const int row = r0 + tid;
    const int lab = label[row >> 3];
    float dot = 0.f;
    #pragma unroll
    for (int kk = 0; kk < 8; ++kk) {
      const size_t qc = ((size_t)(row >> 4) * 8 + kk) * 64 + (row & 15);
      const size_t ac = ((size_t)(lab >> 4) * 8 + kk) * 64 + (lab & 15);
      #pragma unroll
      for (int qd = 0; qd < 4; ++qd) {
        bf16x8 qv = qb[qc + qd * 16];
        bf16x8 av = bb[ac + qd * 16];
        #pragma unroll
        for (int j = 0; j < 8; ++j) dot = fmaf(bf2f(qv[j]), bf2f(av[j]), dot);
      }
    }
    slabws[row] = fmaf(dot, 2.f * L2E, cb[lab]);
  }
}

// ---------------------------------------------------------------------------
// merge (r25, unchanged): 8-way chunk merge + loss/prec1 finalize.
// ---------------------------------------------------------------------------
__global__ __launch_bounds__(256) void proto_merge(
    const float* __restrict__ partm, const float* __restrict__ parts,
    const int* __restrict__ partbi, const float* __restrict__ slabws,
    const int* __restrict__ label,
    float* __restrict__ accum, int* __restrict__ fincount,
    float* __restrict__ out) {
  const int tid = threadIdx.x, row = blockIdx.x * 256 + tid;
  const int wid = tid >> 6;

  float mm = partm[row], sv = parts[row];
  int   b  = partbi[row];
  #pragma unroll
  for (int c = 1; c < 8; ++c) {                      // chunks in ascending cols
    float om = partm[c * NROW + row], os = parts[c * NROW + row];
    int   oi = partbi[c * NROW + row];
    float nm = fmaxf(mm, om);
    sv = sv * exp2f(mm - nm) + os * exp2f(om - nm);
    bool better = (om > mm) || (om == mm && oi < b);
    b = better ? oi : b;
    mm = nm;
  }

  const int lb = label[row >> 3];
  float loss = LN2 * (mm + log2f(sv) - slabws[row]);
  float corr = (b == lb) ? 1.f : 0.f;

  #pragma unroll
  for (int mask = 32; mask; mask >>= 1) {
    loss += __shfl_xor(loss, mask);
    corr += __shfl_xor(corr, mask);
  }
  __shared__ float red[2][4];
  if ((tid & 63) == 0) { red[0][wid] = loss; red[1][wid] = corr; }
  __syncthreads();
  if (tid == 0) {
    float L = red[0][0] + red[0][1] + red[0][2] + red[0][3];
    float C = red[1][0] + red[1][1] + red[1][2] + red[1][3];
    atomicAdd(&accum[0], L);
    atomicAdd(&accum[1], C);
    __threadfence();
    if (atomicAdd(fincount, 1) == (int)gridDim.x - 1) {
      out[0] = atomicAdd(&accum[0], 0.f) / (float)NROW;     // coherent reads
      out[1] = atomicAdd(&accum[1], 0.f) * 100.f / (float)NROW;
    }
  }
}

// ---------------------------------------------------------------------------
extern "C" void kernel_launch(void* const* d_in, const int* in_sizes, int n_in,
                              void* d_out, int out_size, void* d_ws, size_t ws_size,
                              hipStream_t stream) {
  const float* x     = (const float*)d_in[0];
  const int*   label = (const int*)d_in[1];
  float* out = (float*)d_out;

  // ws layout: [0:2) accum | [2] fincount | [16,16+NCOL) cb |
  // Asw (NCOL*DD ushort) | Qsw (NROW*DD ushort) | partm[8N] | parts[8N] |
  // partbi[8N] | slab[N]  (~1.7 MB)
  float*  W        = (float*)d_ws;
  float*  accum    = W;
  int*    fincount = (int*)(W + 2);
  float*  cb       = W + 16;
  ushort* Asw      = (ushort*)(cb + NCOL);
  ushort* Qsw      = Asw + (size_t)NCOL * DD;
  float*  partm    = (float*)(Qsw + (size_t)NROW * DD);
  float*  parts    = partm + 8 * NROW;
  int*    partbi   = (int*)(parts + 8 * NROW);
  float*  slabws   = (float*)(partbi + 8 * NROW);

  hipLaunchKernelGGL(proto_prep, dim3(NEP / 4), dim3(256), 0, stream,
                     x, cb, Asw, Qsw, accum, fincount);
  hipLaunchKernelGGL(proto_main, dim3(512), dim3(256), 0, stream,
                     Qsw, Asw, cb, label, partm, parts, partbi, slabws);
  hipLaunchKernelGGL(proto_merge, dim3(NROW / 256), dim3(256), 0, stream,
                     partm, parts, partbi, slabws, label, accum, fincount, out);
}